// Round 7
// baseline (127.174 us; speedup 1.0000x reference)
//
#include <hip/hip_runtime.h>
#include <hip/hip_bf16.h>

typedef _Float16 f16;
typedef _Float16 f16x4 __attribute__((ext_vector_type(4)));
typedef _Float16 f16x8 __attribute__((ext_vector_type(8)));
typedef float f32x4 __attribute__((ext_vector_type(4)));

#define MFMA(a, b, c) __builtin_amdgcn_mfma_f32_16x16x32_f16((a), (b), (c), 0, 0, 0)

#define BB 4
#define NPOS 32768
#define HH 4
#define NBLK 1024          // blocks of 128 positions
#define STATB 2304         // t[32][32] f16 (2048 B) + s[32][4] f16 (256 B)
#define LDP 136            // padded f16 row stride (272 B, b128-aligned)

__device__ __forceinline__ f16x8 ldx8(const float* p) {
  float4 a = *(const float4*)p;
  float4 b = *(const float4*)(p + 4);
  return (f16x8){(f16)a.x, (f16)a.y, (f16)a.z, (f16)a.w,
                 (f16)b.x, (f16)b.y, (f16)b.z, (f16)b.w};
}

// ---------------------------------------------------------------------------
// k0: weight prep -> f16 transposed layouts ([n][k] rows)
// ---------------------------------------------------------------------------
__global__ __launch_bounds__(256)
void la_k0_prep(const float* __restrict__ wqkv, const float* __restrict__ wout,
                f16* __restrict__ wkvT, f16* __restrict__ wqT,
                f16* __restrict__ woutT) {
  const int g0 = blockIdx.x * 256 + threadIdx.x;
  for (int i = g0; i < HH * 64 * 128; i += 16384) {
    int c = i & 127, n = (i >> 7) & 63, h = i >> 13;
    int col = (n < 32) ? (128 + h * 32 + n) : (256 + h * 32 + (n - 32));
    wkvT[i] = (f16)wqkv[c * 384 + col];
  }
  for (int i = g0; i < HH * 32 * 128; i += 16384) {
    int c = i & 127, n = (i >> 7) & 31, h = i >> 12;
    wqT[i] = (f16)wqkv[c * 384 + h * 32 + n];
  }
  for (int i = g0; i < 128 * 128; i += 16384) {
    int k = i & 127, n = i >> 7;
    woutT[i] = (f16)wout[k * 128 + n];
  }
}

// ---------------------------------------------------------------------------
// k1: k,v logits via MFMA; e = exp(k) (m=0, exact by shift-invariance);
// partial t = E.V^T via MFMA. 2-deep head pipeline, 1 barrier/head.
// ---------------------------------------------------------------------------
__global__ __launch_bounds__(256, 4)
void la_k1_stats(const float* __restrict__ x, const f16* __restrict__ wkvT,
                 char* __restrict__ stats) {
  const int blk = blockIdx.x, t = threadIdx.x;
  const int w = t >> 6, l = t & 63, lg = l >> 4, ln = l & 15;

  __shared__ __align__(16) f16 EV[2][64 * LDP];  // E rows 0-31, V rows 32-63

  const float* xb = x + (size_t)blk * (128 * 128);
  f16x8 xf[2][4];
#pragma unroll
  for (int mi = 0; mi < 2; ++mi)
#pragma unroll
    for (int ks = 0; ks < 4; ++ks)
      xf[mi][ks] = ldx8(xb + (32 * w + 16 * mi + ln) * 128 + 32 * ks + 8 * lg);

  const f32x4 Z4 = {0.f, 0.f, 0.f, 0.f};

  auto logits = [&](int h, f32x4 (&acc)[2][4]) {
#pragma unroll
    for (int mi = 0; mi < 2; ++mi)
#pragma unroll
      for (int nt = 0; nt < 4; ++nt) acc[mi][nt] = Z4;
    const f16* wb = wkvT + h * (64 * 128);
#pragma unroll
    for (int ks = 0; ks < 4; ++ks) {
#pragma unroll
      for (int nt = 0; nt < 4; ++nt) {
        f16x8 bf = *(const f16x8*)(wb + (16 * nt + ln) * 128 + 32 * ks + 8 * lg);
        acc[0][nt] = MFMA(xf[0][ks], bf, acc[0][nt]);
        acc[1][nt] = MFMA(xf[1][ks], bf, acc[1][nt]);
      }
    }
  };

  auto phaseA = [&](int h, f32x4 (&acc)[2][4]) {  // exp + EV store + s stats
    f16* E = (f16*)EV[h & 1];
    float sl[2] = {0.f, 0.f};
#pragma unroll
    for (int nt = 0; nt < 2; ++nt)
#pragma unroll
      for (int mi = 0; mi < 2; ++mi) {
        float e0 = __expf(acc[mi][nt][0]);
        float e1 = __expf(acc[mi][nt][1]);
        float e2 = __expf(acc[mi][nt][2]);
        float e3 = __expf(acc[mi][nt][3]);
        sl[nt] += (e0 + e1) + (e2 + e3);
        *(f16x4*)&E[(16 * nt + ln) * LDP + 32 * w + 16 * mi + 4 * lg] =
            (f16x4){(f16)e0, (f16)e1, (f16)e2, (f16)e3};
        f32x4 vv = acc[mi][nt + 2];
        *(f16x4*)&E[(32 + 16 * nt + ln) * LDP + 32 * w + 16 * mi + 4 * lg] =
            (f16x4){(f16)vv[0], (f16)vv[1], (f16)vv[2], (f16)vv[3]};
      }
#pragma unroll
    for (int nt = 0; nt < 2; ++nt) {
      sl[nt] += __shfl_xor(sl[nt], 16);
      sl[nt] += __shfl_xor(sl[nt], 32);
    }
    f16* sp = (f16*)(stats + (size_t)(blk * HH + h) * STATB + 2048);
    if (lg == 0) {
      sp[ln * 4 + w] = (f16)sl[0];
      sp[(16 + ln) * 4 + w] = (f16)sl[1];
    }
  };

  auto phaseB = [&](int h) {  // barrier + t-MFMA + t store
    __syncthreads();
    const f16* E = (const f16*)EV[h & 1];
    const int tm = w >> 1, tn = w & 1;
    f32x4 tacc = Z4;
#pragma unroll
    for (int ks = 0; ks < 4; ++ks) {
      f16x8 ea = *(const f16x8*)&E[(16 * tm + ln) * LDP + 32 * ks + 8 * lg];
      f16x8 vb = *(const f16x8*)&E[(32 + 16 * tn + ln) * LDP + 32 * ks + 8 * lg];
      tacc = MFMA(ea, vb, tacc);
    }
    f16* tp = (f16*)(stats + (size_t)(blk * HH + h) * STATB);
#pragma unroll
    for (int r = 0; r < 4; ++r)
      tp[(16 * tm + 4 * lg + r) * 32 + 16 * tn + ln] = (f16)tacc[r];
  };

  f32x4 accA[2][4], accB[2][4];
  logits(0, accA);
  phaseA(0, accA); logits(1, accB); phaseB(0);
  phaseA(1, accB); logits(2, accA); phaseB(1);
  phaseA(2, accA); logits(3, accB); phaseB(2);
  phaseA(3, accB); phaseB(3);
}

// ---------------------------------------------------------------------------
// k2: block per (b,h,d): plain sum of 256 chunk stats -> ctxN[bh][d][e] f16
// ---------------------------------------------------------------------------
__global__ __launch_bounds__(256)
void la_k2_combine(const char* __restrict__ stats, f16* __restrict__ ctxN) {
  const int gid = blockIdx.x;  // bh*32 + d
  const int bh = gid >> 5, d = gid & 31;
  const int b = bh >> 2, h = bh & 3;
  const int t = threadIdx.x, w = t >> 6, l = t & 63;
  const int c = t & 31, grp = t >> 5;
  __shared__ float redt[4][32];
  __shared__ float reds[4];

  float sg = 0.f, tc = 0.f;
  for (int i = grp; i < 256; i += 8) {
    const char* ub = stats + (size_t)((b * 256 + i) * HH + h) * STATB;
    tc += (float)((const f16*)ub)[d * 32 + c];
    f16x4 s4 = *(const f16x4*)(ub + 2048 + d * 8);
    sg += ((float)s4[0] + (float)s4[1]) + ((float)s4[2] + (float)s4[3]);
  }
  tc += __shfl_xor(tc, 32);
  sg += __shfl_xor(sg, 32);
  if (l < 32) redt[w][l] = tc;
  if (l == 0) reds[w] = sg;
  __syncthreads();
  if (t < 32) {
    float tt = (redt[0][t] + redt[1][t]) + (redt[2][t] + redt[3][t]);
    float ss = (reds[0] + reds[1]) + (reds[2] + reds[3]);
    // ctxN[bh][d][e] (row d, col e=t)
    ctxN[((size_t)bh * 32 + d) * 32 + t] = (f16)(tt / ss);
  }
}

// ---------------------------------------------------------------------------
// k2b: fold out-conv through attention: GT[b][c][32h+d] = sum_e
//      ctxN[bh][d][e] * wout[32h+e][c]  (A = woutT rows c, B = ctxN rows d)
// ---------------------------------------------------------------------------
__global__ __launch_bounds__(256)
void la_k2b_fold(const f16* __restrict__ ctxN, const f16* __restrict__ woutT,
                 f16* __restrict__ GT) {
  const int b = blockIdx.x, t = threadIdx.x;
  const int h = t >> 6, l = t & 63, lg = l >> 4, ln = l & 15;
  const f32x4 Z4 = {0.f, 0.f, 0.f, 0.f};

  const f16* cb = ctxN + (size_t)((b * HH + h) * 32) * 32;
  f16x8 bfrag[2];
#pragma unroll
  for (int nt = 0; nt < 2; ++nt)
    bfrag[nt] = *(const f16x8*)(cb + (16 * nt + ln) * 32 + 8 * lg);

  f16* gb = GT + (size_t)b * (128 * 128);
#pragma unroll
  for (int mt = 0; mt < 8; ++mt) {
    f16x8 af = *(const f16x8*)(woutT + (16 * mt + ln) * 128 + 32 * h + 8 * lg);
#pragma unroll
    for (int nt = 0; nt < 2; ++nt) {
      f32x4 acc = MFMA(af, bfrag[nt], Z4);
#pragma unroll
      for (int r = 0; r < 4; ++r)
        gb[(size_t)(16 * mt + 4 * lg + r) * 128 + 32 * h + 16 * nt + ln] =
            (f16)acc[r];
    }
  }
}

// ---------------------------------------------------------------------------
// k3: swapped q-logits -> lane-local softmax (m=0) -> Qs[pos][hd] ->
// per-head partial y += Qhat_h . GT_h  (out-conv folded; no PV/Os stage)
// -> fused LN, nontemporal store. Zero barriers, 2-stream pipeline.
// ---------------------------------------------------------------------------
__global__ __launch_bounds__(256, 4)
void la_k3_out(const float* __restrict__ x, const f16* __restrict__ wqT,
               const f16* __restrict__ GT, const float* __restrict__ bout,
               const float* __restrict__ lns, const float* __restrict__ lnb,
               float* __restrict__ out) {
  const int blk = blockIdx.x, t = threadIdx.x;
  const int w = t >> 6, l = t & 63, lg = l >> 4, ln = l & 15;
  const int b = blk >> 8;

  __shared__ __align__(16) f16 Qs[128 * LDP];  // rows pos (wave-private), cols hd

  const float* xb = x + (size_t)blk * (128 * 128);
  f16x8 xf[2][4];  // X as B-fragments: col(pos) = 32w+16nt+ln
#pragma unroll
  for (int nt = 0; nt < 2; ++nt)
#pragma unroll
    for (int ks = 0; ks < 4; ++ks)
      xf[nt][ks] = ldx8(xb + (32 * w + 16 * nt + ln) * 128 + 32 * ks + 8 * lg);

  const f32x4 Z4 = {0.f, 0.f, 0.f, 0.f};
  const f16* gb = GT + (size_t)b * (128 * 128);

  f32x4 y[2][8];
#pragma unroll
  for (int mi = 0; mi < 2; ++mi)
#pragma unroll
    for (int nt = 0; nt < 8; ++nt) y[mi][nt] = Z4;

  auto qlog = [&](int h, f32x4 (&qa)[2][2]) {  // swapped q-logits qT[d][pos]
#pragma unroll
    for (int mt = 0; mt < 2; ++mt)
#pragma unroll
      for (int nt = 0; nt < 2; ++nt) qa[mt][nt] = Z4;
    const f16* wq = wqT + h * (32 * 128);
#pragma unroll
    for (int ks = 0; ks < 4; ++ks) {
      f16x8 a0 = *(const f16x8*)(wq + ln * 128 + 32 * ks + 8 * lg);
      f16x8 a1 = *(const f16x8*)(wq + (16 + ln) * 128 + 32 * ks + 8 * lg);
#pragma unroll
      for (int nt = 0; nt < 2; ++nt) {
        qa[0][nt] = MFMA(a0, xf[nt][ks], qa[0][nt]);
        qa[1][nt] = MFMA(a1, xf[nt][ks], qa[1][nt]);
      }
    }
  };

  auto consume = [&](int h, f32x4 (&qa)[2][2]) {  // softmax -> Qs[pos][32h+d]
#pragma unroll
    for (int nt = 0; nt < 2; ++nt) {
      float s = 0.f;
#pragma unroll
      for (int mt = 0; mt < 2; ++mt)
#pragma unroll
        for (int r = 0; r < 4; ++r) {
          qa[mt][nt][r] = __expf(qa[mt][nt][r]);
          s += qa[mt][nt][r];
        }
      s += __shfl_xor(s, 16);
      s += __shfl_xor(s, 32);
      const float inv = 0.17677669529663688f / s;  // 32^-0.5 / sum
#pragma unroll
      for (int mt = 0; mt < 2; ++mt) {
        *(f16x4*)&Qs[(32 * w + 16 * nt + ln) * LDP + 32 * h + 16 * mt + 4 * lg] =
            (f16x4){(f16)(qa[mt][nt][0] * inv), (f16)(qa[mt][nt][1] * inv),
                    (f16)(qa[mt][nt][2] * inv), (f16)(qa[mt][nt][3] * inv)};
      }
    }
  };

  auto ymfma = [&](int h) {  // y[pos][c] += Qhat[pos][32h..] * GT[c][32h..]
#pragma unroll
    for (int mi = 0; mi < 2; ++mi) {
      f16x8 af = *(const f16x8*)&Qs[(32 * w + 16 * mi + ln) * LDP + 32 * h + 8 * lg];
#pragma unroll
      for (int nt = 0; nt < 8; ++nt) {
        f16x8 bf = *(const f16x8*)(gb + (16 * nt + ln) * 128 + 32 * h + 8 * lg);
        y[mi][nt] = MFMA(af, bf, y[mi][nt]);
      }
    }
  };

  f32x4 qaA[2][2], qaB[2][2];
  qlog(0, qaA);
  consume(0, qaA); qlog(1, qaB); ymfma(0);
  consume(1, qaB); qlog(2, qaA); ymfma(1);
  consume(2, qaA); qlog(3, qaB); ymfma(2);
  consume(3, qaB); ymfma(3);

  // bias + LayerNorm + nontemporal store
  float bv[8], sv[8], b2[8];
#pragma unroll
  for (int nt = 0; nt < 8; ++nt) {
    int col = 16 * nt + ln;
    bv[nt] = bout[col];
    sv[nt] = lns[col];
    b2[nt] = lnb[col];
  }
#pragma unroll
  for (int mi = 0; mi < 2; ++mi)
#pragma unroll
    for (int r = 0; r < 4; ++r) {
      float sum = 0.f;
#pragma unroll
      for (int nt = 0; nt < 8; ++nt) {
        y[mi][nt][r] += bv[nt];
        sum += y[mi][nt][r];
      }
      sum += __shfl_xor(sum, 1);
      sum += __shfl_xor(sum, 2);
      sum += __shfl_xor(sum, 4);
      sum += __shfl_xor(sum, 8);
      const float mean = sum * (1.f / 128.f);
      float var = 0.f;
#pragma unroll
      for (int nt = 0; nt < 8; ++nt) {
        float dv = y[mi][nt][r] - mean;
        var = fmaf(dv, dv, var);
      }
      var += __shfl_xor(var, 1);
      var += __shfl_xor(var, 2);
      var += __shfl_xor(var, 4);
      var += __shfl_xor(var, 8);
      const float inv = rsqrtf(var * (1.f / 128.f) + 1e-6f);
      const int pos = blk * 128 + 32 * w + 16 * mi + 4 * lg + r;
      float* op = out + (size_t)pos * 128;
#pragma unroll
      for (int nt = 0; nt < 8; ++nt)
        __builtin_nontemporal_store(
            (y[mi][nt][r] - mean) * inv * sv[nt] + b2[nt], &op[16 * nt + ln]);
    }
}

// ---------------------------------------------------------------------------
extern "C" void kernel_launch(void* const* d_in, const int* in_sizes, int n_in,
                              void* d_out, int out_size, void* d_ws, size_t ws_size,
                              hipStream_t stream) {
  const float* x = (const float*)d_in[0];
  const float* w_qkv = (const float*)d_in[1];
  const float* w_out = (const float*)d_in[2];
  const float* b_out = (const float*)d_in[3];
  const float* ln_s = (const float*)d_in[4];
  const float* ln_b = (const float*)d_in[5];
  float* out = (float*)d_out;

  char* ws = (char*)d_ws;
  char* stats = ws;                                   // 4096*2304 = 9437184 B
  f16* wkvT = (f16*)(ws + 9437184);                   // 65536 B
  f16* wqT = (f16*)(ws + 9437184 + 65536);            // 32768 B
  f16* woutT = (f16*)(ws + 9437184 + 65536 + 32768);  // 32768 B
  f16* ctxN = (f16*)(ws + 9437184 + 65536 + 32768 + 32768);  // 32768 B
  // GT (4*128*128 f16 = 131072 B) aliases the stats region: stats are fully
  // consumed by k2 before k2b writes GT (stream-ordered), re-written by k1
  // next call -> deterministic.
  f16* GT = (f16*)ws;

  la_k0_prep<<<dim3(64), 256, 0, stream>>>(w_qkv, w_out, wkvT, wqT, woutT);
  la_k1_stats<<<dim3(NBLK), 256, 0, stream>>>(x, wkvT, stats);
  la_k2_combine<<<dim3(512), 256, 0, stream>>>(stats, ctxN);
  la_k2b_fold<<<dim3(BB), 256, 0, stream>>>(ctxN, woutT, GT);
  la_k3_out<<<dim3(NBLK), 256, 0, stream>>>(x, wqT, GT, b_out, ln_s, ln_b, out);
}

// Round 8
// 86.682 us; speedup vs baseline: 1.4671x; 1.4671x over previous
//
#include <hip/hip_runtime.h>
#include <hip/hip_bf16.h>

typedef _Float16 f16;
typedef _Float16 f16x4 __attribute__((ext_vector_type(4)));
typedef _Float16 f16x8 __attribute__((ext_vector_type(8)));
typedef float f32x4 __attribute__((ext_vector_type(4)));

#define MFMA(a, b, c) __builtin_amdgcn_mfma_f32_16x16x32_f16((a), (b), (c), 0, 0, 0)

#define BB 4
#define NPOS 32768
#define HH 4
#define NBLK 1024          // blocks of 128 positions
#define STATB 2304         // t[32][32] f16 (2048 B) + s[32][4] f16 (256 B)
#define LDP 136            // padded f16 row stride for EV (272 B)
#define LDQ 40             // Qs row stride (80 B, b128-aligned)

__device__ __forceinline__ f16x8 ldx8(const float* p) {
  float4 a = *(const float4*)p;
  float4 b = *(const float4*)(p + 4);
  return (f16x8){(f16)a.x, (f16)a.y, (f16)a.z, (f16)a.w,
                 (f16)b.x, (f16)b.y, (f16)b.z, (f16)b.w};
}

// ---------------------------------------------------------------------------
// k0: weight prep. wkvF/wqF in FRAGMENT-MAJOR order: chunk*512 f16 + lane*8,
// so a wave's fragment load is one contiguous 1 KB read.
//   wkvF chunk = (h*4+nt)*4+ks ; lane(l) holds n=16nt+(l&15), c=32ks+8(l>>4)+j
//   wqF  chunk = (h*2+a)*4+ks  ; lane(l) holds n=16a+(l&15),  c=32ks+8(l>>4)+j
// woutT stays row-major [cout][hid] (only k2b reads it).
// ---------------------------------------------------------------------------
__global__ __launch_bounds__(256)
void la_k0_prep(const float* __restrict__ wqkv, const float* __restrict__ wout,
                f16* __restrict__ wkvF, f16* __restrict__ wqF,
                f16* __restrict__ woutT) {
  const int g0 = blockIdx.x * 256 + threadIdx.x;  // 16384 threads
  for (int i = g0; i < 32768; i += 16384) {
    int j = i & 7, l = (i >> 3) & 63, ks = (i >> 9) & 3, nt = (i >> 11) & 3,
        h = i >> 13;
    int n = 16 * nt + (l & 15);
    int c = 32 * ks + 8 * (l >> 4) + j;
    int col = (n < 32) ? (128 + h * 32 + n) : (256 + h * 32 + (n - 32));
    wkvF[i] = (f16)wqkv[c * 384 + col];
  }
  {
    int i = g0;  // 16384 elements, one per thread
    int j = i & 7, l = (i >> 3) & 63, ks = (i >> 9) & 3, a = (i >> 11) & 1,
        h = i >> 12;
    int n = 16 * a + (l & 15);
    int c = 32 * ks + 8 * (l >> 4) + j;
    wqF[i] = (f16)wqkv[c * 384 + h * 32 + n];
  }
  if (g0 < 128 * 128) {
    int k = g0 & 127, n = g0 >> 7;
    woutT[g0] = (f16)wout[k * 128 + n];
  }
}

// ---------------------------------------------------------------------------
// k1: k,v logits via MFMA (fragment-major wkvF: contiguous 1 KB loads);
// e = exp(k) (m=0, exact by shift-invariance); partial t = E.V^T via MFMA.
// 2-deep head pipeline, 1 barrier/head.
// ---------------------------------------------------------------------------
__global__ __launch_bounds__(256, 4)
void la_k1_stats(const float* __restrict__ x, const f16* __restrict__ wkvF,
                 char* __restrict__ stats) {
  const int blk = blockIdx.x, t = threadIdx.x;
  const int w = t >> 6, l = t & 63, lg = l >> 4, ln = l & 15;

  __shared__ __align__(16) f16 EV[2][64 * LDP];  // E rows 0-31, V rows 32-63

  const float* xb = x + (size_t)blk * (128 * 128);
  f16x8 xf[2][4];
#pragma unroll
  for (int mi = 0; mi < 2; ++mi)
#pragma unroll
    for (int ks = 0; ks < 4; ++ks)
      xf[mi][ks] = ldx8(xb + (32 * w + 16 * mi + ln) * 128 + 32 * ks + 8 * lg);

  const f32x4 Z4 = {0.f, 0.f, 0.f, 0.f};

  auto logits = [&](int h, f32x4 (&acc)[2][4]) {
#pragma unroll
    for (int mi = 0; mi < 2; ++mi)
#pragma unroll
      for (int nt = 0; nt < 4; ++nt) acc[mi][nt] = Z4;
#pragma unroll
    for (int ks = 0; ks < 4; ++ks) {
#pragma unroll
      for (int nt = 0; nt < 4; ++nt) {
        f16x8 bf = *(const f16x8*)(wkvF + (((h * 4 + nt) * 4 + ks) << 9) + l * 8);
        acc[0][nt] = MFMA(xf[0][ks], bf, acc[0][nt]);
        acc[1][nt] = MFMA(xf[1][ks], bf, acc[1][nt]);
      }
    }
  };

  auto phaseA = [&](int h, f32x4 (&acc)[2][4]) {  // exp + EV store + s stats
    f16* E = (f16*)EV[h & 1];
    float sl[2] = {0.f, 0.f};
#pragma unroll
    for (int nt = 0; nt < 2; ++nt)
#pragma unroll
      for (int mi = 0; mi < 2; ++mi) {
        float e0 = __expf(acc[mi][nt][0]);
        float e1 = __expf(acc[mi][nt][1]);
        float e2 = __expf(acc[mi][nt][2]);
        float e3 = __expf(acc[mi][nt][3]);
        sl[nt] += (e0 + e1) + (e2 + e3);
        *(f16x4*)&E[(16 * nt + ln) * LDP + 32 * w + 16 * mi + 4 * lg] =
            (f16x4){(f16)e0, (f16)e1, (f16)e2, (f16)e3};
        f32x4 vv = acc[mi][nt + 2];
        *(f16x4*)&E[(32 + 16 * nt + ln) * LDP + 32 * w + 16 * mi + 4 * lg] =
            (f16x4){(f16)vv[0], (f16)vv[1], (f16)vv[2], (f16)vv[3]};
      }
#pragma unroll
    for (int nt = 0; nt < 2; ++nt) {
      sl[nt] += __shfl_xor(sl[nt], 16);
      sl[nt] += __shfl_xor(sl[nt], 32);
    }
    f16* sp = (f16*)(stats + (size_t)(blk * HH + h) * STATB + 2048);
    if (lg == 0) {
      sp[ln * 4 + w] = (f16)sl[0];
      sp[(16 + ln) * 4 + w] = (f16)sl[1];
    }
  };

  auto phaseB = [&](int h) {  // barrier + t-MFMA + t store
    __syncthreads();
    const f16* E = (const f16*)EV[h & 1];
    const int tm = w >> 1, tn = w & 1;
    f32x4 tacc = Z4;
#pragma unroll
    for (int ks = 0; ks < 4; ++ks) {
      f16x8 ea = *(const f16x8*)&E[(16 * tm + ln) * LDP + 32 * ks + 8 * lg];
      f16x8 vb = *(const f16x8*)&E[(32 + 16 * tn + ln) * LDP + 32 * ks + 8 * lg];
      tacc = MFMA(ea, vb, tacc);
    }
    f16* tp = (f16*)(stats + (size_t)(blk * HH + h) * STATB);
#pragma unroll
    for (int r = 0; r < 4; ++r)
      tp[(16 * tm + 4 * lg + r) * 32 + 16 * tn + ln] = (f16)tacc[r];
  };

  f32x4 accA[2][4], accB[2][4];
  logits(0, accA);
  phaseA(0, accA); logits(1, accB); phaseB(0);
  phaseA(1, accB); logits(2, accA); phaseB(1);
  phaseA(2, accA); logits(3, accB); phaseB(2);
  phaseA(3, accB); phaseB(3);
}

// ---------------------------------------------------------------------------
// k2: block per (b,h,d): plain sum of 256 chunk stats -> ctxN[bh][d][e] f16
// ---------------------------------------------------------------------------
__global__ __launch_bounds__(256)
void la_k2_combine(const char* __restrict__ stats, f16* __restrict__ ctxN) {
  const int gid = blockIdx.x;  // bh*32 + d
  const int bh = gid >> 5, d = gid & 31;
  const int b = bh >> 2, h = bh & 3;
  const int t = threadIdx.x, w = t >> 6, l = t & 63;
  const int c = t & 31, grp = t >> 5;
  __shared__ float redt[4][32];
  __shared__ float reds[4];

  float sg = 0.f, tc = 0.f;
  for (int i = grp; i < 256; i += 8) {
    const char* ub = stats + (size_t)((b * 256 + i) * HH + h) * STATB;
    tc += (float)((const f16*)ub)[d * 32 + c];
    f16x4 s4 = *(const f16x4*)(ub + 2048 + d * 8);
    sg += ((float)s4[0] + (float)s4[1]) + ((float)s4[2] + (float)s4[3]);
  }
  tc += __shfl_xor(tc, 32);
  sg += __shfl_xor(sg, 32);
  if (l < 32) redt[w][l] = tc;
  if (l == 0) reds[w] = sg;
  __syncthreads();
  if (t < 32) {
    float tt = (redt[0][t] + redt[1][t]) + (redt[2][t] + redt[3][t]);
    float ss = (reds[0] + reds[1]) + (reds[2] + reds[3]);
    ctxN[((size_t)bh * 32 + d) * 32 + t] = (f16)(tt / ss);
  }
}

// ---------------------------------------------------------------------------
// k2b: GT[b][c][32h+d] = sum_e ctxN[bh][d][e] * wout[32h+e][c]  (row-major GT)
// ---------------------------------------------------------------------------
__global__ __launch_bounds__(256)
void la_k2b_fold(const f16* __restrict__ ctxN, const f16* __restrict__ woutT,
                 f16* __restrict__ GT) {
  const int b = blockIdx.x, t = threadIdx.x;
  const int h = t >> 6, l = t & 63, lg = l >> 4, ln = l & 15;
  const f32x4 Z4 = {0.f, 0.f, 0.f, 0.f};

  const f16* cb = ctxN + (size_t)((b * HH + h) * 32) * 32;
  f16x8 bfrag[2];
#pragma unroll
  for (int nt = 0; nt < 2; ++nt)
    bfrag[nt] = *(const f16x8*)(cb + (16 * nt + ln) * 32 + 8 * lg);

  f16* gb = GT + (size_t)b * (128 * 128);
#pragma unroll
  for (int mt = 0; mt < 8; ++mt) {
    f16x8 af = *(const f16x8*)(woutT + (16 * mt + ln) * 128 + 32 * h + 8 * lg);
#pragma unroll
    for (int nt = 0; nt < 2; ++nt) {
      f32x4 acc = MFMA(af, bfrag[nt], Z4);
#pragma unroll
      for (int r = 0; r < 4; ++r)
        gb[(size_t)(16 * mt + 4 * lg + r) * 128 + 32 * h + 16 * nt + ln] =
            (f16)acc[r];
    }
  }
}

// ---------------------------------------------------------------------------
// k3: stage GT->LDS (fragment-major, one barrier); swapped q-logits
// (contiguous wqF loads) -> lane-local softmax -> Qs -> y += Qhat.GT from LDS
// -> fused LN, plain store.
// ---------------------------------------------------------------------------
__global__ __launch_bounds__(256, 3)
void la_k3_out(const float* __restrict__ x, const f16* __restrict__ wqF,
               const f16* __restrict__ GT, const float* __restrict__ bout,
               const float* __restrict__ lns, const float* __restrict__ lnb,
               float* __restrict__ out) {
  const int blk = blockIdx.x, t = threadIdx.x;
  const int w = t >> 6, l = t & 63, lg = l >> 4, ln = l & 15;
  const int b = blk >> 8;

  __shared__ __align__(16) f16 GTs[16384];      // fragment-major, 32 KB
  __shared__ __align__(16) f16 Qs[128 * LDQ];   // per-head, wave-private rows

  // ---- stage GT (row-major global) -> GTs (fragment-major) ----
  {
    const f16* gbm = GT + (size_t)b * (128 * 128);
#pragma unroll
    for (int i = 0; i < 8; ++i) {
      int idx = i * 256 + t;        // f16x8 slot 0..2047
      int row = idx >> 4;           // c
      int col8 = idx & 15;          // hd/8
      f16x8 v = *(const f16x8*)(gbm + row * 128 + col8 * 8);
      int chunk = (col8 >> 2) * 8 + (row >> 4);
      int slot = (col8 & 3) * 16 + (row & 15);
      *(f16x8*)&GTs[(chunk << 9) + slot * 8] = v;
    }
  }

  const float* xb = x + (size_t)blk * (128 * 128);
  f16x8 xf[2][4];  // X as B-fragments: col(pos) = 32w+16nt+ln
#pragma unroll
  for (int nt = 0; nt < 2; ++nt)
#pragma unroll
    for (int ks = 0; ks < 4; ++ks)
      xf[nt][ks] = ldx8(xb + (32 * w + 16 * nt + ln) * 128 + 32 * ks + 8 * lg);

  const f32x4 Z4 = {0.f, 0.f, 0.f, 0.f};

  f32x4 y[2][8];
#pragma unroll
  for (int mi = 0; mi < 2; ++mi)
#pragma unroll
    for (int nt = 0; nt < 8; ++nt) y[mi][nt] = Z4;

  auto qlog = [&](int h, f32x4 (&qa)[2][2]) {  // swapped q-logits qT[d][pos]
#pragma unroll
    for (int mt = 0; mt < 2; ++mt)
#pragma unroll
      for (int nt = 0; nt < 2; ++nt) qa[mt][nt] = Z4;
#pragma unroll
    for (int ks = 0; ks < 4; ++ks) {
      f16x8 a0 = *(const f16x8*)(wqF + (((h * 2 + 0) * 4 + ks) << 9) + l * 8);
      f16x8 a1 = *(const f16x8*)(wqF + (((h * 2 + 1) * 4 + ks) << 9) + l * 8);
#pragma unroll
      for (int nt = 0; nt < 2; ++nt) {
        qa[0][nt] = MFMA(a0, xf[nt][ks], qa[0][nt]);
        qa[1][nt] = MFMA(a1, xf[nt][ks], qa[1][nt]);
      }
    }
  };

  auto consume = [&](int h, f32x4 (&qa)[2][2]) {  // softmax -> Qs[pos][d]
#pragma unroll
    for (int nt = 0; nt < 2; ++nt) {
      float s = 0.f;
#pragma unroll
      for (int mt = 0; mt < 2; ++mt)
#pragma unroll
        for (int r = 0; r < 4; ++r) {
          qa[mt][nt][r] = __expf(qa[mt][nt][r]);
          s += qa[mt][nt][r];
        }
      s += __shfl_xor(s, 16);
      s += __shfl_xor(s, 32);
      const float inv = 0.17677669529663688f / s;  // 32^-0.5 / sum
#pragma unroll
      for (int mt = 0; mt < 2; ++mt) {
        *(f16x4*)&Qs[(32 * w + 16 * nt + ln) * LDQ + 16 * mt + 4 * lg] =
            (f16x4){(f16)(qa[mt][nt][0] * inv), (f16)(qa[mt][nt][1] * inv),
                    (f16)(qa[mt][nt][2] * inv), (f16)(qa[mt][nt][3] * inv)};
      }
    }
  };

  auto ymfma = [&](int h) {  // y[pos][c] += Qhat[pos][d] * GT[c][32h+d]
#pragma unroll
    for (int mi = 0; mi < 2; ++mi) {
      f16x8 af = *(const f16x8*)&Qs[(32 * w + 16 * mi + ln) * LDQ + 8 * lg];
#pragma unroll
      for (int nt = 0; nt < 8; ++nt) {
        f16x8 bf = *(const f16x8*)&GTs[((h * 8 + nt) << 9) + l * 8];
        y[mi][nt] = MFMA(af, bf, y[mi][nt]);
      }
    }
  };

  f32x4 qaA[2][2], qaB[2][2];
  qlog(0, qaA);
  consume(0, qaA);
  qlog(1, qaB);
  __syncthreads();  // GTs staged (Qs is wave-private: no barrier needed)
  ymfma(0);
  consume(1, qaB); qlog(2, qaA); ymfma(1);
  consume(2, qaA); qlog(3, qaB); ymfma(2);
  consume(3, qaB); ymfma(3);

  // bias + LayerNorm + store
  float bv[8], sv[8], b2[8];
#pragma unroll
  for (int nt = 0; nt < 8; ++nt) {
    int col = 16 * nt + ln;
    bv[nt] = bout[col];
    sv[nt] = lns[col];
    b2[nt] = lnb[col];
  }
#pragma unroll
  for (int mi = 0; mi < 2; ++mi)
#pragma unroll
    for (int r = 0; r < 4; ++r) {
      float sum = 0.f;
#pragma unroll
      for (int nt = 0; nt < 8; ++nt) {
        y[mi][nt][r] += bv[nt];
        sum += y[mi][nt][r];
      }
      sum += __shfl_xor(sum, 1);
      sum += __shfl_xor(sum, 2);
      sum += __shfl_xor(sum, 4);
      sum += __shfl_xor(sum, 8);
      const float mean = sum * (1.f / 128.f);
      float var = 0.f;
#pragma unroll
      for (int nt = 0; nt < 8; ++nt) {
        float dv = y[mi][nt][r] - mean;
        var = fmaf(dv, dv, var);
      }
      var += __shfl_xor(var, 1);
      var += __shfl_xor(var, 2);
      var += __shfl_xor(var, 4);
      var += __shfl_xor(var, 8);
      const float inv = rsqrtf(var * (1.f / 128.f) + 1e-6f);
      const int pos = blk * 128 + 32 * w + 16 * mi + 4 * lg + r;
      float* op = out + (size_t)pos * 128;
#pragma unroll
      for (int nt = 0; nt < 8; ++nt)
        op[16 * nt + ln] = (y[mi][nt][r] - mean) * inv * sv[nt] + b2[nt];
    }
}

// ---------------------------------------------------------------------------
extern "C" void kernel_launch(void* const* d_in, const int* in_sizes, int n_in,
                              void* d_out, int out_size, void* d_ws, size_t ws_size,
                              hipStream_t stream) {
  const float* x = (const float*)d_in[0];
  const float* w_qkv = (const float*)d_in[1];
  const float* w_out = (const float*)d_in[2];
  const float* b_out = (const float*)d_in[3];
  const float* ln_s = (const float*)d_in[4];
  const float* ln_b = (const float*)d_in[5];
  float* out = (float*)d_out;

  char* ws = (char*)d_ws;
  char* stats = ws;                                   // 4096*2304 = 9437184 B
  f16* wkvF = (f16*)(ws + 9437184);                   // 65536 B
  f16* wqF = (f16*)(ws + 9437184 + 65536);            // 32768 B
  f16* woutT = (f16*)(ws + 9437184 + 65536 + 32768);  // 32768 B
  f16* ctxN = (f16*)(ws + 9437184 + 65536 + 32768 + 32768);  // 32768 B
  // GT (4*128*128 f16 = 131072 B) aliases the stats region: stats fully
  // consumed by k2 before k2b writes GT (stream-ordered) -> deterministic.
  f16* GT = (f16*)ws;

  la_k0_prep<<<dim3(64), 256, 0, stream>>>(w_qkv, w_out, wkvF, wqF, woutT);
  la_k1_stats<<<dim3(NBLK), 256, 0, stream>>>(x, wkvF, stats);
  la_k2_combine<<<dim3(512), 256, 0, stream>>>(stats, ctxN);
  la_k2b_fold<<<dim3(BB), 256, 0, stream>>>(ctxN, woutT, GT);
  la_k3_out<<<dim3(NBLK), 256, 0, stream>>>(x, wqF, GT, b_out, ln_s, ln_b, out);
}

// Round 9
// 85.606 us; speedup vs baseline: 1.4856x; 1.0126x over previous
//
#include <hip/hip_runtime.h>
#include <hip/hip_bf16.h>

typedef _Float16 f16;
typedef _Float16 f16x4 __attribute__((ext_vector_type(4)));
typedef _Float16 f16x8 __attribute__((ext_vector_type(8)));
typedef float f32x4 __attribute__((ext_vector_type(4)));

#define MFMA(a, b, c) __builtin_amdgcn_mfma_f32_16x16x32_f16((a), (b), (c), 0, 0, 0)

#define BB 4
#define NPOS 32768
#define HH 4
#define NBLK 1024          // blocks of 128 positions
#define STATB 2304         // t[32][32] f16 (2048 B) + s[32][4] f16 (256 B)
#define LDP 136            // padded f16 row stride for EV (272 B)

__device__ __forceinline__ f16x8 ldx8(const float* p) {
  float4 a = *(const float4*)p;
  float4 b = *(const float4*)(p + 4);
  return (f16x8){(f16)a.x, (f16)a.y, (f16)a.z, (f16)a.w,
                 (f16)b.x, (f16)b.y, (f16)b.z, (f16)b.w};
}

// ---------------------------------------------------------------------------
// k0: weight prep, fragment-major (chunk*512 f16 + lane*8 = contiguous 1 KB
// per wave-fragment).
//   wkvF chunk = (h*4+nt)*4+ks ; lane l: n = 16nt+(l&15), c = 32ks+8(l>>4)+j
//   wqF  chunk = (h*2+a)*4+ks  ; lane l: n = SIGMA(a, l&15), c = 32ks+8(l>>4)+j
//     SIGMA places feature d' = 8*(i>>2)+4a+(i&3) at A-row i, so the q-logit
//     MFMA output lands with lane (lg,ln) holding d = 8lg+4mt+r = the exact
//     A-fragment k-slots for the y-MFMA (j = 4mt+r). No LDS transpose needed.
// ---------------------------------------------------------------------------
__global__ __launch_bounds__(256)
void la_k0_prep(const float* __restrict__ wqkv, const float* __restrict__ wout,
                f16* __restrict__ wkvF, f16* __restrict__ wqF,
                f16* __restrict__ woutT) {
  const int g0 = blockIdx.x * 256 + threadIdx.x;  // 16384 threads
  for (int i = g0; i < 32768; i += 16384) {
    int j = i & 7, l = (i >> 3) & 63, ks = (i >> 9) & 3, nt = (i >> 11) & 3,
        h = i >> 13;
    int n = 16 * nt + (l & 15);
    int c = 32 * ks + 8 * (l >> 4) + j;
    int col = (n < 32) ? (128 + h * 32 + n) : (256 + h * 32 + (n - 32));
    wkvF[i] = (f16)wqkv[c * 384 + col];
  }
  {
    int i = g0;  // 16384 elements, one per thread
    int j = i & 7, l = (i >> 3) & 63, ks = (i >> 9) & 3, a = (i >> 11) & 1,
        h = i >> 12;
    int row = l & 15;
    int n = 8 * (row >> 2) + 4 * a + (row & 3);  // SIGMA permutation
    int c = 32 * ks + 8 * (l >> 4) + j;
    wqF[i] = (f16)wqkv[c * 384 + h * 32 + n];
  }
  if (g0 < 128 * 128) {
    int k = g0 & 127, n = g0 >> 7;
    woutT[g0] = (f16)wout[k * 128 + n];
  }
}

// ---------------------------------------------------------------------------
// k1: k,v logits via MFMA (fragment-major wkvF); e = exp(k) (m=0, exact by
// shift-invariance); partial t = E.V^T via MFMA. 2-deep pipeline, 1 bar/head.
// ---------------------------------------------------------------------------
__global__ __launch_bounds__(256, 4)
void la_k1_stats(const float* __restrict__ x, const f16* __restrict__ wkvF,
                 char* __restrict__ stats) {
  const int blk = blockIdx.x, t = threadIdx.x;
  const int w = t >> 6, l = t & 63, lg = l >> 4, ln = l & 15;

  __shared__ __align__(16) f16 EV[2][64 * LDP];  // E rows 0-31, V rows 32-63

  const float* xb = x + (size_t)blk * (128 * 128);
  f16x8 xf[2][4];
#pragma unroll
  for (int mi = 0; mi < 2; ++mi)
#pragma unroll
    for (int ks = 0; ks < 4; ++ks)
      xf[mi][ks] = ldx8(xb + (32 * w + 16 * mi + ln) * 128 + 32 * ks + 8 * lg);

  const f32x4 Z4 = {0.f, 0.f, 0.f, 0.f};

  auto logits = [&](int h, f32x4 (&acc)[2][4]) {
#pragma unroll
    for (int mi = 0; mi < 2; ++mi)
#pragma unroll
      for (int nt = 0; nt < 4; ++nt) acc[mi][nt] = Z4;
#pragma unroll
    for (int ks = 0; ks < 4; ++ks) {
#pragma unroll
      for (int nt = 0; nt < 4; ++nt) {
        f16x8 bf = *(const f16x8*)(wkvF + (((h * 4 + nt) * 4 + ks) << 9) + l * 8);
        acc[0][nt] = MFMA(xf[0][ks], bf, acc[0][nt]);
        acc[1][nt] = MFMA(xf[1][ks], bf, acc[1][nt]);
      }
    }
  };

  auto phaseA = [&](int h, f32x4 (&acc)[2][4]) {  // exp + EV store + s stats
    f16* E = (f16*)EV[h & 1];
    float sl[2] = {0.f, 0.f};
#pragma unroll
    for (int nt = 0; nt < 2; ++nt)
#pragma unroll
      for (int mi = 0; mi < 2; ++mi) {
        float e0 = __expf(acc[mi][nt][0]);
        float e1 = __expf(acc[mi][nt][1]);
        float e2 = __expf(acc[mi][nt][2]);
        float e3 = __expf(acc[mi][nt][3]);
        sl[nt] += (e0 + e1) + (e2 + e3);
        *(f16x4*)&E[(16 * nt + ln) * LDP + 32 * w + 16 * mi + 4 * lg] =
            (f16x4){(f16)e0, (f16)e1, (f16)e2, (f16)e3};
        f32x4 vv = acc[mi][nt + 2];
        *(f16x4*)&E[(32 + 16 * nt + ln) * LDP + 32 * w + 16 * mi + 4 * lg] =
            (f16x4){(f16)vv[0], (f16)vv[1], (f16)vv[2], (f16)vv[3]};
      }
#pragma unroll
    for (int nt = 0; nt < 2; ++nt) {
      sl[nt] += __shfl_xor(sl[nt], 16);
      sl[nt] += __shfl_xor(sl[nt], 32);
    }
    f16* sp = (f16*)(stats + (size_t)(blk * HH + h) * STATB + 2048);
    if (lg == 0) {
      sp[ln * 4 + w] = (f16)sl[0];
      sp[(16 + ln) * 4 + w] = (f16)sl[1];
    }
  };

  auto phaseB = [&](int h) {  // barrier + t-MFMA + t store
    __syncthreads();
    const f16* E = (const f16*)EV[h & 1];
    const int tm = w >> 1, tn = w & 1;
    f32x4 tacc = Z4;
#pragma unroll
    for (int ks = 0; ks < 4; ++ks) {
      f16x8 ea = *(const f16x8*)&E[(16 * tm + ln) * LDP + 32 * ks + 8 * lg];
      f16x8 vb = *(const f16x8*)&E[(32 + 16 * tn + ln) * LDP + 32 * ks + 8 * lg];
      tacc = MFMA(ea, vb, tacc);
    }
    f16* tp = (f16*)(stats + (size_t)(blk * HH + h) * STATB);
#pragma unroll
    for (int r = 0; r < 4; ++r)
      tp[(16 * tm + 4 * lg + r) * 32 + 16 * tn + ln] = (f16)tacc[r];
  };

  f32x4 accA[2][4], accB[2][4];
  logits(0, accA);
  phaseA(0, accA); logits(1, accB); phaseB(0);
  phaseA(1, accB); logits(2, accA); phaseB(1);
  phaseA(2, accA); logits(3, accB); phaseB(2);
  phaseA(3, accB); phaseB(3);
}

// ---------------------------------------------------------------------------
// k2: block per (b,h,d): plain sum of 256 chunk stats -> ctxN[bh][d][e] f16
// ---------------------------------------------------------------------------
__global__ __launch_bounds__(256)
void la_k2_combine(const char* __restrict__ stats, f16* __restrict__ ctxN) {
  const int gid = blockIdx.x;  // bh*32 + d
  const int bh = gid >> 5, d = gid & 31;
  const int b = bh >> 2, h = bh & 3;
  const int t = threadIdx.x, w = t >> 6, l = t & 63;
  const int c = t & 31, grp = t >> 5;
  __shared__ float redt[4][32];
  __shared__ float reds[4];

  float sg = 0.f, tc = 0.f;
  for (int i = grp; i < 256; i += 8) {
    const char* ub = stats + (size_t)((b * 256 + i) * HH + h) * STATB;
    tc += (float)((const f16*)ub)[d * 32 + c];
    f16x4 s4 = *(const f16x4*)(ub + 2048 + d * 8);
    sg += ((float)s4[0] + (float)s4[1]) + ((float)s4[2] + (float)s4[3]);
  }
  tc += __shfl_xor(tc, 32);
  sg += __shfl_xor(sg, 32);
  if (l < 32) redt[w][l] = tc;
  if (l == 0) reds[w] = sg;
  __syncthreads();
  if (t < 32) {
    float tt = (redt[0][t] + redt[1][t]) + (redt[2][t] + redt[3][t]);
    float ss = (reds[0] + reds[1]) + (reds[2] + reds[3]);
    ctxN[((size_t)bh * 32 + d) * 32 + t] = (f16)(tt / ss);
  }
}

// ---------------------------------------------------------------------------
// k2b: GT fold, written FRAGMENT-MAJOR to global:
//   GTF[b][(h*8+mt)*512 + l'*8 + j] = GT[c=16mt+(l'&15)][hd=32h+8(l'>>4)+j]
// so k3's B-fragment load is one contiguous 1 KB wave read.
// ---------------------------------------------------------------------------
__global__ __launch_bounds__(256)
void la_k2b_fold(const f16* __restrict__ ctxN, const f16* __restrict__ woutT,
                 f16* __restrict__ GTF) {
  const int b = blockIdx.x, t = threadIdx.x;
  const int h = t >> 6, l = t & 63, lg = l >> 4, ln = l & 15;
  const f32x4 Z4 = {0.f, 0.f, 0.f, 0.f};

  const f16* cb = ctxN + (size_t)((b * HH + h) * 32) * 32;
  f16x8 bfrag[2];
#pragma unroll
  for (int nt = 0; nt < 2; ++nt)
    bfrag[nt] = *(const f16x8*)(cb + (16 * nt + ln) * 32 + 8 * lg);

  f16* gf = GTF + (size_t)b * 16384;
#pragma unroll
  for (int mt = 0; mt < 8; ++mt) {
    f16x8 af = *(const f16x8*)(woutT + (16 * mt + ln) * 128 + 32 * h + 8 * lg);
#pragma unroll
    for (int nt = 0; nt < 2; ++nt) {
      f32x4 acc = MFMA(af, bfrag[nt], Z4);
      // lane holds GT(c = 16mt+4lg+r, d = 16nt+ln); scatter to frag-major
#pragma unroll
      for (int r = 0; r < 4; ++r) {
        int dsub = 16 * nt + ln;
        gf[((h * 8 + mt) << 9) + (16 * (dsub >> 3) + 4 * lg + r) * 8 + (dsub & 7)] =
            (f16)acc[r];
      }
    }
  }
}

// ---------------------------------------------------------------------------
// k3: swapped q-logits (SIGMA-permuted wqF) -> lane-local softmax -> af pack
// IN REGISTER -> y += af . GTF-frag (global, L2-hot) -> fused LN.
// ZERO LDS, ZERO barriers.
// ---------------------------------------------------------------------------
__global__ __launch_bounds__(256, 4)
void la_k3_out(const float* __restrict__ x, const f16* __restrict__ wqF,
               const f16* __restrict__ GTF, const float* __restrict__ bout,
               const float* __restrict__ lns, const float* __restrict__ lnb,
               float* __restrict__ out) {
  const int blk = blockIdx.x, t = threadIdx.x;
  const int w = t >> 6, l = t & 63, lg = l >> 4, ln = l & 15;
  const int b = blk >> 8;

  const float* xb = x + (size_t)blk * (128 * 128);
  f16x8 xf[2][4];  // X as B-fragments: col(pos) = 32w+16nt+ln
#pragma unroll
  for (int nt = 0; nt < 2; ++nt)
#pragma unroll
    for (int ks = 0; ks < 4; ++ks)
      xf[nt][ks] = ldx8(xb + (32 * w + 16 * nt + ln) * 128 + 32 * ks + 8 * lg);

  const f32x4 Z4 = {0.f, 0.f, 0.f, 0.f};
  const f16* gf = GTF + (size_t)b * 16384;

  f32x4 y[2][8];
#pragma unroll
  for (int mi = 0; mi < 2; ++mi)
#pragma unroll
    for (int nt = 0; nt < 8; ++nt) y[mi][nt] = Z4;

  auto qlog = [&](int h, f32x4 (&qa)[2][2]) {  // qT[d][pos], d SIGMA-permuted
#pragma unroll
    for (int mt = 0; mt < 2; ++mt)
#pragma unroll
      for (int nt = 0; nt < 2; ++nt) qa[mt][nt] = Z4;
#pragma unroll
    for (int ks = 0; ks < 4; ++ks) {
      f16x8 a0 = *(const f16x8*)(wqF + (((h * 2 + 0) * 4 + ks) << 9) + l * 8);
      f16x8 a1 = *(const f16x8*)(wqF + (((h * 2 + 1) * 4 + ks) << 9) + l * 8);
#pragma unroll
      for (int nt = 0; nt < 2; ++nt) {
        qa[0][nt] = MFMA(a0, xf[nt][ks], qa[0][nt]);
        qa[1][nt] = MFMA(a1, xf[nt][ks], qa[1][nt]);
      }
    }
  };

  // softmax over d (m=0) + in-register A-fragment pack:
  // lane (lg,ln) holds d = 8lg+4mt+r for pos = 16nt+ln -> af[nt] k-slot j=4mt+r
  auto consume = [&](f32x4 (&qa)[2][2], f16x8 (&af)[2]) {
#pragma unroll
    for (int nt = 0; nt < 2; ++nt) {
      float s = 0.f;
#pragma unroll
      for (int mt = 0; mt < 2; ++mt)
#pragma unroll
        for (int r = 0; r < 4; ++r) {
          qa[mt][nt][r] = __expf(qa[mt][nt][r]);
          s += qa[mt][nt][r];
        }
      s += __shfl_xor(s, 16);
      s += __shfl_xor(s, 32);
      const float inv = 0.17677669529663688f / s;  // 32^-0.5 / sum
      af[nt] = (f16x8){(f16)(qa[0][nt][0] * inv), (f16)(qa[0][nt][1] * inv),
                       (f16)(qa[0][nt][2] * inv), (f16)(qa[0][nt][3] * inv),
                       (f16)(qa[1][nt][0] * inv), (f16)(qa[1][nt][1] * inv),
                       (f16)(qa[1][nt][2] * inv), (f16)(qa[1][nt][3] * inv)};
    }
  };

  auto ymfma = [&](int h, f16x8 (&af)[2]) {  // y[pos][c] += Qhat . GT_h
#pragma unroll
    for (int nc = 0; nc < 8; ++nc) {
      f16x8 bf = *(const f16x8*)(gf + (((h * 8 + nc) << 9) + l * 8));
      y[0][nc] = MFMA(af[0], bf, y[0][nc]);
      y[1][nc] = MFMA(af[1], bf, y[1][nc]);
    }
  };

  f32x4 qaA[2][2], qaB[2][2];
  f16x8 afA[2], afB[2];
  qlog(0, qaA); qlog(1, qaB);
  consume(qaA, afA); ymfma(0, afA); qlog(2, qaA);
  consume(qaB, afB); ymfma(1, afB); qlog(3, qaB);
  consume(qaA, afA); ymfma(2, afA);
  consume(qaB, afB); ymfma(3, afB);

  // bias + LayerNorm + store
  float bv[8], sv[8], b2[8];
#pragma unroll
  for (int nt = 0; nt < 8; ++nt) {
    int col = 16 * nt + ln;
    bv[nt] = bout[col];
    sv[nt] = lns[col];
    b2[nt] = lnb[col];
  }
#pragma unroll
  for (int mi = 0; mi < 2; ++mi)
#pragma unroll
    for (int r = 0; r < 4; ++r) {
      float sum = 0.f;
#pragma unroll
      for (int nt = 0; nt < 8; ++nt) {
        y[mi][nt][r] += bv[nt];
        sum += y[mi][nt][r];
      }
      sum += __shfl_xor(sum, 1);
      sum += __shfl_xor(sum, 2);
      sum += __shfl_xor(sum, 4);
      sum += __shfl_xor(sum, 8);
      const float mean = sum * (1.f / 128.f);
      float var = 0.f;
#pragma unroll
      for (int nt = 0; nt < 8; ++nt) {
        float dv = y[mi][nt][r] - mean;
        var = fmaf(dv, dv, var);
      }
      var += __shfl_xor(var, 1);
      var += __shfl_xor(var, 2);
      var += __shfl_xor(var, 4);
      var += __shfl_xor(var, 8);
      const float inv = rsqrtf(var * (1.f / 128.f) + 1e-6f);
      const int pos = blk * 128 + 32 * w + 16 * mi + 4 * lg + r;
      float* op = out + (size_t)pos * 128;
#pragma unroll
      for (int nt = 0; nt < 8; ++nt)
        op[16 * nt + ln] = (y[mi][nt][r] - mean) * inv * sv[nt] + b2[nt];
    }
}

// ---------------------------------------------------------------------------
extern "C" void kernel_launch(void* const* d_in, const int* in_sizes, int n_in,
                              void* d_out, int out_size, void* d_ws, size_t ws_size,
                              hipStream_t stream) {
  const float* x = (const float*)d_in[0];
  const float* w_qkv = (const float*)d_in[1];
  const float* w_out = (const float*)d_in[2];
  const float* b_out = (const float*)d_in[3];
  const float* ln_s = (const float*)d_in[4];
  const float* ln_b = (const float*)d_in[5];
  float* out = (float*)d_out;

  char* ws = (char*)d_ws;
  char* stats = ws;                                   // 4096*2304 = 9437184 B
  f16* wkvF = (f16*)(ws + 9437184);                   // 65536 B
  f16* wqF = (f16*)(ws + 9437184 + 65536);            // 32768 B
  f16* woutT = (f16*)(ws + 9437184 + 65536 + 32768);  // 32768 B
  f16* ctxN = (f16*)(ws + 9437184 + 65536 + 32768 + 32768);  // 32768 B
  // GTF (4*16384 f16 = 131072 B) aliases the stats region: stats fully
  // consumed by k2 before k2b writes GTF (stream-ordered) -> deterministic.
  f16* GTF = (f16*)ws;

  la_k0_prep<<<dim3(64), 256, 0, stream>>>(w_qkv, w_out, wkvF, wqF, woutT);
  la_k1_stats<<<dim3(NBLK), 256, 0, stream>>>(x, wkvF, stats);
  la_k2_combine<<<dim3(512), 256, 0, stream>>>(stats, ctxN);
  la_k2b_fold<<<dim3(BB), 256, 0, stream>>>(ctxN, woutT, GTF);
  la_k3_out<<<dim3(NBLK), 256, 0, stream>>>(x, wqF, GTF, b_out, ln_s, ln_b, out);
}